// Round 10
// baseline (231.584 us; speedup 1.0000x reference)
//
#include <hip/hip_runtime.h>
#include <math.h>

#define BATCH 8
#define CH    256
#define H     128
#define W     128
#define HW    (H * W)          // 16384
#define OH    65
#define OW    65
#define NPIX  (OH * OW)        // 4225

// ---------------- K1: channel L2 norms, pure stream ----------------
// 512 blocks (2/CU) x 256 thr (4 waves). Block = 256-pixel tile of one image;
// wave wv covers channels [wv*64, wv*64+64). Per channel the wave reads
// 1 KB contiguous; 64 independent loads/lane -> deep pipeline.
__global__ __launch_bounds__(256) void norm_kernel(const float4* __restrict__ x4,
                                                   float* __restrict__ nrm) {
    const int b    = blockIdx.x >> 6;      // 0..7
    const int t    = blockIdx.x & 63;      // 256-px tile within image
    const int lane = threadIdx.x & 63;
    const int wv   = threadIdx.x >> 6;     // 0..3

    const float4* p = x4 + (size_t)(b * CH + wv * 64) * (HW / 4) + t * 64 + lane;
    float4 a = {0.f, 0.f, 0.f, 0.f};
    #pragma unroll 8
    for (int c = 0; c < 64; ++c) {
        float4 v = p[(size_t)c * (HW / 4)];
        a.x += v.x * v.x; a.y += v.y * v.y;
        a.z += v.z * v.z; a.w += v.w * v.w;
    }
    __shared__ float part[4][256];
    ((float4*)part[wv])[lane] = a;         // flat px index = 4*lane+comp
    __syncthreads();
    float s = part[0][threadIdx.x] + part[1][threadIdx.x]
            + part[2][threadIdx.x] + part[3][threadIdx.x];
    nrm[(size_t)b * HW + t * 256 + threadIdx.x] = sqrtf(s);
}

// ---------------- K1.5: softmax weights in per-lane S/T layout ----------------
// Grid 8*65 blocks x 128 thr. Block (b, oh): threads <65 compute the verified
// softmax weight sets into LDS; threads <64 scatter into the component-major
// per-lane layout wbuf[((b*OH+oh)*9 + k)*64 + lane]:
//   k0..k2 = T weights (set[l][2], set[l][5], set[l][8])
//   k3..k8 = S weights (set[l+1][0],[1],[3],[4],[6],[7])
// so K2's weight fetch is 9 coalesced dword loads, no validity logic.
__global__ __launch_bounds__(128) void weights_kernel(const float* __restrict__ nrm,
                                                      float* __restrict__ wbuf) {
    const int b  = blockIdx.x & 7;
    const int oh = blockIdx.x >> 3;        // 0..64
    const int t  = threadIdx.x;

    __shared__ float ws[OH][9];
    if (t < OH) {
        const int ow  = t;
        const int iw0 = ow * 2 - 2;
        const float* nb = nrm + (size_t)b * HW;
        float nv[9]; bool val[9]; float m = 0.0f;
        #pragma unroll
        for (int kh = 0; kh < 3; ++kh) {
            int ih = oh * 2 + kh - 2;
            bool vh = (unsigned)ih < (unsigned)H;
            #pragma unroll
            for (int kw = 0; kw < 3; ++kw) {
                int iw = iw0 + kw;
                int k  = kh * 3 + kw;
                bool v = vh && ((unsigned)iw < (unsigned)W);
                val[k] = v;
                nv[k]  = v ? nb[ih * W + iw] : 0.0f;
                m = fmaxf(m, nv[k]);
            }
        }
        float denom = 0.0f, wt[9];
        #pragma unroll
        for (int k = 0; k < 9; ++k) {
            float e = __expf(nv[k] - m);
            denom += e;
            wt[k] = val[k] ? e : 0.0f;
        }
        float inv = 1.0f / denom;
        #pragma unroll
        for (int k = 0; k < 9; ++k) ws[ow][k] = wt[k] * inv;
    }
    __syncthreads();

    if (t < 64) {
        float k0 = ws[t][2],     k1 = ws[t][5],     k2 = ws[t][8];
        float k3 = ws[t + 1][0], k4 = ws[t + 1][1];
        float k5 = ws[t + 1][3], k6 = ws[t + 1][4];
        float k7 = ws[t + 1][6], k8 = ws[t + 1][7];
        float* wp = wbuf + (size_t)(b * OH + oh) * 9 * 64 + t;
        wp[0]   = k0; wp[64]  = k1; wp[128] = k2;
        wp[192] = k3; wp[256] = k4; wp[320] = k5;
        wp[384] = k6; wp[448] = k7; wp[512] = k8;
    }
}

// ---------------- K2a: pooling as a pure sequential stream ----------------
// 512 blocks (2/CU) x 256 thr; wave = one channel plane (c = (bid>>3)*4 + wv).
// Rolling rows: oh needs input rows (2oh-2, 2oh-1, 2oh); row 2oh-2 is the
// previous iteration's row 2oh (register), so exactly 2 NEW rows load per
// step, ascending address order -> each 64 KB plane read once, sequentially.
// Rows -2/-1 (oh=0) and 128 (oh=64) have zero weights baked into wbuf.
// Verified S/T decomposition: lane l owns cols (2l, 2l+1);
//   out[l] = T_l + S_{l-1} (shfl_up);  out[0] = T_0;  out[64] = S_63.
__global__ __launch_bounds__(256) void pool_stream_kernel(
        const float* __restrict__ x, const float* __restrict__ wbuf,
        float* __restrict__ out) {
    const int b    = blockIdx.x & 7;       // XCD pin: image -> XCD
    const int g    = blockIdx.x >> 3;      // 0..63 channel group
    const int lane = threadIdx.x & 63;
    const int wv   = threadIdx.x >> 6;     // 0..3
    const int c    = g * 4 + wv;

    const float2* xr = (const float2*)(x + (size_t)(b * CH + c) * HW);
    float*        op = out + (size_t)(b * CH + c) * NPIX;
    const float*  wb = wbuf + (size_t)b * OH * 9 * 64 + lane;

    float2 v2 = xr[lane];                  // row 0
    float2 v0 = v2, v1 = v2;               // rows -2,-1: weights are zero

    #pragma unroll 4
    for (int oh = 0; oh < OH; ++oh) {
        const float* wk = wb + oh * (9 * 64);
        float k0 = wk[0],   k1 = wk[64],  k2 = wk[128];
        float k3 = wk[192], k4 = wk[256], k5 = wk[320];
        float k6 = wk[384], k7 = wk[448], k8 = wk[512];
        if (oh > 0) {
            v0 = v2;                                    // row 2oh-2
            v1 = xr[(2 * oh - 1) * 64 + lane];          // row 2oh-1
            int r2 = (2 * oh < H) ? 2 * oh : H - 1;     // row 2oh (128 -> wt 0)
            v2 = xr[r2 * 64 + lane];
        }
        float T = k0 * v0.x + k1 * v1.x + k2 * v2.x;    // -> out[lane]
        float S = k3 * v0.x + k4 * v0.y
                + k5 * v1.x + k6 * v1.y
                + k7 * v2.x + k8 * v2.y;                // -> out[lane+1]
        float Sp = __shfl_up(S, 1);
        float res = (lane == 0) ? T : T + Sp;
        op[oh * OW + lane] = res;                       // coalesced 260B run
        if (lane == 63) op[oh * OW + 64] = S;           // ow = 64
    }
}

// ---------------- K2b: FALLBACK pool (R7-verified, 512 KB ws only) ----------
#define K2TPB 256
#define CPW   32
#define CGC   128

__global__ __launch_bounds__(K2TPB) void pool_inline_kernel(
        const float* __restrict__ x, const float* __restrict__ nrm,
        float* __restrict__ out) {
    const int b   = blockIdx.x & 7;
    const int rem = blockIdx.x >> 3;       // 0..129
    const int oh  = rem % OH;
    const int cg  = rem / OH;              // 0 or 1
    const int tid  = threadIdx.x;
    const int lane = tid & 63;
    const int wv   = tid >> 6;

    int  rowc[3];
    #pragma unroll
    for (int r = 0; r < 3; ++r) {
        int ih = oh * 2 + r - 2;
        rowc[r] = ih < 0 ? 0 : (ih > H - 1 ? H - 1 : ih);
    }

    __shared__ float ns[3][W];
    __shared__ float wls[OH][9];

    for (int id = tid; id < 3 * W; id += K2TPB) {
        int r = id >> 7, col = id & (W - 1);
        ns[r][col] = nrm[(size_t)b * HW + rowc[r] * W + col];
    }
    __syncthreads();

    if (tid < OH) {
        const int ow  = tid;
        const int iw0 = ow * 2 - 2;
        float nv[9]; bool val[9]; float m = 0.0f;
        #pragma unroll
        for (int kh = 0; kh < 3; ++kh) {
            int ih = oh * 2 + kh - 2;
            bool vh = (unsigned)ih < (unsigned)H;
            #pragma unroll
            for (int kw = 0; kw < 3; ++kw) {
                int iw = iw0 + kw;
                int k  = kh * 3 + kw;
                bool v = vh && ((unsigned)iw < (unsigned)W);
                val[k] = v;
                nv[k]  = v ? ns[kh][iw] : 0.0f;
                m = fmaxf(m, nv[k]);
            }
        }
        float denom = 0.0f, wt[9];
        #pragma unroll
        for (int k = 0; k < 9; ++k) {
            float e = __expf(nv[k] - m);
            denom += e;
            wt[k] = val[k] ? e : 0.0f;
        }
        float inv = 1.0f / denom;
        #pragma unroll
        for (int k = 0; k < 9; ++k) wls[ow][k] = wt[k] * inv;
    }
    __syncthreads();

    const float wA0 = wls[lane][2], wA1 = wls[lane][5], wA2 = wls[lane][8];
    const float wB0 = wls[lane + 1][0], wC0 = wls[lane + 1][1];
    const float wB1 = wls[lane + 1][3], wC1 = wls[lane + 1][4];
    const float wB2 = wls[lane + 1][6], wC2 = wls[lane + 1][7];

    const float2* xw2 = (const float2*)x
        + (size_t)(b * CH + cg * CGC + wv * CPW) * (HW / 2);
    const int base0 = rowc[0] * (W / 2) + lane;
    const int base1 = rowc[1] * (W / 2) + lane;
    const int base2 = rowc[2] * (W / 2) + lane;

    float* ob = out + (size_t)(b * CH + cg * CGC + wv * CPW) * NPIX
                    + (size_t)oh * OW;
    #pragma unroll 8
    for (int c = 0; c < CPW; ++c) {
        const size_t cb = (size_t)c * (HW / 2);
        float2 v0 = xw2[cb + base0];
        float2 v1 = xw2[cb + base1];
        float2 v2 = xw2[cb + base2];
        float S = wB0 * v0.x + wC0 * v0.y
                + wB1 * v1.x + wC1 * v1.y
                + wB2 * v2.x + wC2 * v2.y;
        float T = wA0 * v0.x + wA1 * v1.x + wA2 * v2.x;
        float Sp = __shfl_up(S, 1);
        float res = (lane == 0) ? T : T + Sp;
        float* oc = ob + (size_t)c * NPIX;
        oc[lane] = res;
        if (lane == 63) oc[64] = S;
    }
}

extern "C" void kernel_launch(void* const* d_in, const int* in_sizes, int n_in,
                              void* d_out, int out_size, void* d_ws, size_t ws_size,
                              hipStream_t stream) {
    const float* x = (const float*)d_in[0];
    float* out  = (float*)d_out;
    float* nbuf = (float*)d_ws;                        // 512 KB norms

    const size_t norm_bytes = (size_t)BATCH * HW * sizeof(float);          // 512 KB
    const size_t wbuf_bytes = (size_t)BATCH * OH * 9 * 64 * sizeof(float); // 1.17 MB

    norm_kernel<<<512, 256, 0, stream>>>((const float4*)x, nbuf);

    if (ws_size >= norm_bytes + wbuf_bytes) {
        // stream path: precomputed per-lane weights + rolling-row sequential pool
        float* wbuf = nbuf + (size_t)BATCH * HW;
        weights_kernel<<<BATCH * OH, 128, 0, stream>>>(nbuf, wbuf);
        pool_stream_kernel<<<512, 256, 0, stream>>>(x, wbuf, out);
    } else {
        // fallback: R7-verified inline-weight pool (needs only the norm buffer)
        pool_inline_kernel<<<BATCH * OH * 2, K2TPB, 0, stream>>>(x, nbuf, out);
    }
}